// Round 13
// baseline (79.069 us; speedup 1.0000x reference)
//
#include <hip/hip_runtime.h>
#include <hip/hip_bf16.h>

// ---------------------------------------------------------------------------
// Sizes (fixed)
// ---------------------------------------------------------------------------
#define BATCH 4
#define NN    256
#define DD    600
#define HH    256
#define MROWS (BATCH*NN)   // 1024
#define KPAD  640          // DD padded to multiple of 64
#define ATTS  272          // P-tile LDS row stride (bf16)

typedef __attribute__((ext_vector_type(8))) short bf16x8;   // 8 bf16 (4 VGPRs)
typedef __attribute__((ext_vector_type(4))) float f32x4;

__device__ __forceinline__ void gload16(const void* g, void* l)
{
    __builtin_amdgcn_global_load_lds(
        (const __attribute__((address_space(1))) void*)g,
        (__attribute__((address_space(3))) void*)l, 16, 0, 0);
}

// counted vmcnt wait; n is compile-time after full unroll -> folds to one inst
__device__ __forceinline__ void waitcnt_vm(int n)
{
    switch (n) {
    case 0:  asm volatile("s_waitcnt vmcnt(0)"  ::: "memory"); break;
    case 3:  asm volatile("s_waitcnt vmcnt(3)"  ::: "memory"); break;
    case 6:  asm volatile("s_waitcnt vmcnt(6)"  ::: "memory"); break;
    default: asm volatile("s_waitcnt vmcnt(0)"  ::: "memory"); break;
    }
}

// XCD-chunked bijective remap (m204) of flattened block id
__device__ __forceinline__ int xcd_remap(int lin, int nwg)
{
    const int q = nwg >> 3, r = nwg & 7;
    const int xcd = lin & 7, off = lin >> 3;
    return (xcd < r ? xcd * (q + 1) : r * (q + 1) + (xcd - r) * q) + off;
}

// ---------------------------------------------------------------------------
// bf16 MFMA GEMM (R11, proven): C = A[M,K] @ BT^T (+bias cols<biasN).
// Tile 64M x 32N x 64K, 4 waves (2x2), wave tile 32x16. Ring-4 LDS,
// 3 gload_lds issues/k-tile, counted vmcnt + raw s_barrier.
// WF32: fp32 C (cols<Nvalid). WB16: bf16 C. WHT: hT[b][d][j] retile.
// ---------------------------------------------------------------------------
template<bool BIAS, bool WF32, bool WB16, bool WHT, int NK>
__global__ __launch_bounds__(256) void gemm_mfma(
    const __hip_bfloat16* __restrict__ A, const __hip_bfloat16* __restrict__ BT,
    const float* __restrict__ bias,
    float* __restrict__ Cf, __hip_bfloat16* __restrict__ Cb,
    __hip_bfloat16* __restrict__ hT,
    int lda, int ldb, int ldcf, int ldcb, int Nvalid, int biasN)
{
    __shared__ __align__(16) char lds[49152];   // A: (t&3)*8K ; B: 32K+(t&3)*4K

    const int nwg = gridDim.x * gridDim.y;
    int lin = xcd_remap(blockIdx.x + gridDim.x * blockIdx.y, nwg);
    const int bx = lin % gridDim.x;
    const int by = lin / gridDim.x;

    const int tid  = threadIdx.x;
    const int lane = tid & 63;
    const int wid  = tid >> 6;
    const int wr   = wid >> 1;          // wave row 0..1 (32 M each)
    const int wc   = wid & 1;           // wave col 0..1 (16 N each)
    const int row0 = by * 64;
    const int col0 = bx * 32;

    const char* Ab = (const char*)A + ((long long)row0 * lda) * 2;
    const char* Bb = (const char*)BT + ((long long)col0 * ldb) * 2;

    const int sr   = tid >> 3;                    // 0..31
    const int scb  = (tid & 7) * 16;              // 0..112
    const int scbs = scb ^ ((sr & 7) << 4);       // inverse source swizzle

    const char* gA0 = Ab + (long long)sr        * (lda * 2) + scbs;
    const char* gA1 = Ab + (long long)(sr + 32) * (lda * 2) + scbs;
    const char* gB0 = Bb + (long long)sr        * (ldb * 2) + scbs;

    f32x4 acc[2] = {};
    const int fr = lane & 15;
    const int kg = (lane >> 4) * 16;
    const int xv = (fr & 7) << 4;       // read-side XOR swizzle

    auto issue = [&](int t) {
        char* bA = lds + (t & 3) * 8192;
        char* bB = lds + 32768 + (t & 3) * 4096;
        const long long off = (long long)t * 128;
        gload16(gA0 + off, bA + wid * 1024);
        gload16(gA1 + off, bA + 4096 + wid * 1024);
        gload16(gB0 + off, bB + wid * 1024);
    };

    constexpr int PRE = (NK < 3) ? NK : 3;
    #pragma unroll
    for (int p = 0; p < PRE; ++p) issue(p);

    #pragma unroll
    for (int t = 0; t < NK; ++t) {
        const int imax = (t + 2 < NK - 1) ? t + 2 : NK - 1;   // last issued tile
        waitcnt_vm(3 * (imax - t));
        __builtin_amdgcn_s_barrier();
        const char* lA = lds + (t & 3) * 8192;
        const char* lB = lds + 32768 + (t & 3) * 4096;
        #pragma unroll
        for (int ks = 0; ks < 2; ++ks) {
            const int kb = ks * 64 + kg;
            bf16x8 a0 = *(const bf16x8*)(lA + (wr * 32 + fr)      * 128 + (kb ^ xv));
            bf16x8 a1 = *(const bf16x8*)(lA + (wr * 32 + 16 + fr) * 128 + (kb ^ xv));
            bf16x8 b0 = *(const bf16x8*)(lB + (wc * 16 + fr)      * 128 + (kb ^ xv));
            acc[0] = __builtin_amdgcn_mfma_f32_16x16x32_bf16(a0, b0, acc[0], 0, 0, 0);
            acc[1] = __builtin_amdgcn_mfma_f32_16x16x32_bf16(a1, b0, acc[1], 0, 0, 0);
        }
        if (t + 3 < NK) issue(t + 3);
    }
    __syncthreads();

    const int er = (lane >> 4) * 4;
    const int ec = lane & 15;
    __hip_bfloat16* sT = (__hip_bfloat16*)lds;   // [64][40] retile buffer

    #pragma unroll
    for (int mi = 0; mi < 2; ++mi) {
        const int lr0 = wr * 32 + mi * 16 + er;
        const int lc  = wc * 16 + ec;
        const int gr = row0 + lr0;
        const int gc = col0 + lc;
        const float bv = (BIAS && gc < biasN) ? bias[gc] : 0.f;
        #pragma unroll
        for (int r = 0; r < 4; ++r) {
            float v = acc[mi][r] + bv;
            const __hip_bfloat16 hv = __float2bfloat16(v);
            const long long row = gr + r;
            if (WF32 && gc < Nvalid)
                Cf[row * ldcf + gc] = v;
            if (WB16)
                Cb[row * ldcb + gc] = hv;
            if (WHT)
                sT[(lr0 + r) * 40 + lc] = hv;
        }
    }

    if (WHT) {
        __syncthreads();
        const int b  = row0 >> 8;
        const int i0 = row0 & 255;
        const int cc = tid >> 3;         // 0..31 (d within tile)
        const int ch = tid & 7;          // j-chunk of 8
        const int d = col0 + cc;
        __align__(16) __hip_bfloat16 tmp[8];
        #pragma unroll
        for (int u = 0; u < 8; ++u)
            tmp[u] = sT[(ch * 8 + u) * 40 + cc];
        *(float4*)&hT[((long long)b * KPAD + d) * NN + i0 + ch * 8] = *(float4*)tmp;
    }
}

// ---------------------------------------------------------------------------
// Prep (unchanged, proven): xb cvt + W0T/W1T/aW1T 32x32 LDS transposes.
// ---------------------------------------------------------------------------
__global__ __launch_bounds__(256) void prep_kernel(
    const float* __restrict__ feature, const float* __restrict__ W0,
    const float* __restrict__ W1, const float* __restrict__ aW1,
    __hip_bfloat16* __restrict__ xb, __hip_bfloat16* __restrict__ W0T,
    __hip_bfloat16* __restrict__ W1T, __hip_bfloat16* __restrict__ aW1T)
{
    const int bid = blockIdx.x;
    const int tid = threadIdx.x;
    if (bid < 640) {
        const int idx = (bid * 256 + tid) * 4;
        const int r = idx / KPAD, c = idx % KPAD;
        float4 v = make_float4(0.f, 0.f, 0.f, 0.f);
        if (c < DD) v = *(const float4*)&feature[r * DD + c];   // DD%4==0
        __align__(8) __hip_bfloat16 o[4] = {
            __float2bfloat16(v.x), __float2bfloat16(v.y),
            __float2bfloat16(v.z), __float2bfloat16(v.w)};
        *(float2*)&xb[idx] = *(float2*)o;
        return;
    }
    __shared__ float tile[32][33];
    const int t = bid - 640;
    const int which = (t < 400) ? 0 : (t < 800) ? 1 : 2;
    const int tt = (which == 0) ? t : (which == 1) ? t - 400 : t - 800;
    const int n0 = (tt / 20) * 32;
    const int k0 = (tt % 20) * 32;
    const int tx = tid & 31, ty = tid >> 5;
    #pragma unroll
    for (int r = 0; r < 4; ++r) {
        const int k = k0 + ty + r * 8;
        const int n = n0 + tx;
        float v = 0.f;
        if (which == 0)      { if (k < DD && n < DD) v = W0[k * DD + n]; }
        else if (which == 1) { if (k < DD && n < DD) v = W1[k * DD + n]; }
        else                 { if (k < DD) v = (n < HH) ? aW1[k * HH + n]
                                                        : aW1[(DD + k) * HH + (n - HH)]; }
        tile[ty + r * 8][tx] = v;
    }
    __syncthreads();
    __hip_bfloat16* dst = (which == 0) ? W0T : (which == 1) ? W1T : aW1T;
    #pragma unroll
    for (int r = 0; r < 4; ++r) {
        const int n = n0 + ty + r * 8;
        const int k = k0 + tx;
        dst[n * KPAD + k] = __float2bfloat16(tile[tx][ty + r * 8]);
    }
}

// ---------------------------------------------------------------------------
// Fused attention + PV v2.
// Score phase: identical to R11 attn_kernel (proven).
// PV phase: out[4][640] = P(4x256 bf16, LDS) @ h[b] — per-wave 160 cols,
// B-fragments loaded DIRECTLY from global hT[b] (L2-resident, shared by all
// 64 blocks of the batch), fully unrolled, no barriers, compiler-scheduled.
// D rows 4..15 are garbage-by-construction and never stored.
// OUTF32: fp32 out[row][<600] ; else bf16 xb[row][640].
// ---------------------------------------------------------------------------
__device__ __forceinline__ void block_max4(float* v, float (*red)[4])
{
    #pragma unroll
    for (int o = 32; o > 0; o >>= 1)
        #pragma unroll
        for (int q = 0; q < 4; ++q) v[q] = fmaxf(v[q], __shfl_down(v[q], o));
    const int lane = threadIdx.x & 63, w = threadIdx.x >> 6;
    if (lane == 0) { red[w][0]=v[0]; red[w][1]=v[1]; red[w][2]=v[2]; red[w][3]=v[3]; }
    __syncthreads();
    #pragma unroll
    for (int q = 0; q < 4; ++q)
        v[q] = fmaxf(fmaxf(red[0][q], red[1][q]), fmaxf(red[2][q], red[3][q]));
    __syncthreads();
}

__device__ __forceinline__ void block_sum4(float* v, float (*red)[4])
{
    #pragma unroll
    for (int o = 32; o > 0; o >>= 1)
        #pragma unroll
        for (int q = 0; q < 4; ++q) v[q] += __shfl_down(v[q], o);
    const int lane = threadIdx.x & 63, w = threadIdx.x >> 6;
    if (lane == 0) { red[w][0]=v[0]; red[w][1]=v[1]; red[w][2]=v[2]; red[w][3]=v[3]; }
    __syncthreads();
    #pragma unroll
    for (int q = 0; q < 4; ++q)
        v[q] = red[0][q] + red[1][q] + red[2][q] + red[3][q];
    __syncthreads();
}

template<bool OUTF32>
__global__ __launch_bounds__(256) void attn_pv(
    const float* __restrict__ LR, const float* __restrict__ aW2,
    const float* __restrict__ ab2, const float* __restrict__ adj,
    const __hip_bfloat16* __restrict__ hT,
    __hip_bfloat16* __restrict__ Ob, float* __restrict__ Of)
{
    __shared__ float sL[4][HH];
    __shared__ float sW[HH];
    __shared__ float red[4][4];
    __shared__ __align__(16) __hip_bfloat16 attl[4 * ATTS];

    const int b  = blockIdx.y;
    const int i0 = blockIdx.x * 4;
    const int j  = threadIdx.x;
    const int lane = threadIdx.x & 63;
    const int wid  = threadIdx.x >> 6;

    // ---------------- score phase (proven, R11) ----------------
    float a[4];
    #pragma unroll
    for (int q = 0; q < 4; ++q)
        a[q] = adj[((long long)(b * NN + i0 + q)) * NN + j];
    const float ab2v = ab2[0];

    sW[j] = aW2[j];
    #pragma unroll
    for (int q = 0; q < 4; ++q)
        sL[q][j] = LR[((long long)(b * NN + i0 + q)) * 512 + j];
    __syncthreads();

    const float* rp = LR + ((long long)(b * NN + j)) * 512 + HH;
    float acs[4] = {0.f, 0.f, 0.f, 0.f};
    for (int h = 0; h < HH; h += 8) {
        const float4 ra = *(const float4*)(rp + h);
        const float4 rb = *(const float4*)(rp + h + 4);
        const float4 w0 = *(const float4*)&sW[h];
        const float4 w1 = *(const float4*)&sW[h + 4];
        #pragma unroll
        for (int q = 0; q < 4; ++q) {
            const float4 l0 = *(const float4*)&sL[q][h];
            const float4 l1 = *(const float4*)&sL[q][h + 4];
            float s = fmaxf(l0.x + ra.x, 0.f) * w0.x;
            s += fmaxf(l0.y + ra.y, 0.f) * w0.y;
            s += fmaxf(l0.z + ra.z, 0.f) * w0.z;
            s += fmaxf(l0.w + ra.w, 0.f) * w0.w;
            s += fmaxf(l1.x + rb.x, 0.f) * w1.x;
            s += fmaxf(l1.y + rb.y, 0.f) * w1.y;
            s += fmaxf(l1.z + rb.z, 0.f) * w1.z;
            s += fmaxf(l1.w + rb.w, 0.f) * w1.w;
            acs[q] += s;
        }
    }

    float m[4];
    #pragma unroll
    for (int q = 0; q < 4; ++q) {
        float e = acs[q] + ab2v;
        e = (e > 0.f) ? e : 0.01f * e;                       // leaky_relu
        m[q] = (a[q] == 0.f) ? -1e9f : e;                    // mask
    }
    float mx[4] = {m[0], m[1], m[2], m[3]};
    block_max4(mx, red);
    float p[4];
    #pragma unroll
    for (int q = 0; q < 4; ++q) p[q] = __expf(m[q] - mx[q]);
    float s4[4] = {p[0], p[1], p[2], p[3]};
    block_sum4(s4, red);

    // P (bf16) -> LDS
    #pragma unroll
    for (int q = 0; q < 4; ++q)
        attl[q * ATTS + j] = __float2bfloat16(p[q] / s4[q] * a[q]);
    __syncthreads();

    // ---------------- PV phase: direct-load MFMA, no barriers -------------
    const char* hTb = (const char*)(hT + (long long)b * KPAD * NN);
    const int fr  = lane & 15;
    const int kgb = (lane >> 4) * 16;          // byte offset within 512B k-row
    const int ar  = (fr < 4) ? fr : 0;         // clamp A row (rows 4-15 unused)
    const char* pa = (const char*)attl + ar * (ATTS * 2) + kgb;
    const int d0w = wid * 160;                 // wave's 160-col slice

    f32x4 acc[10] = {};
    #pragma unroll
    for (int kt = 0; kt < 8; ++kt) {
        const bf16x8 afr = *(const bf16x8*)(pa + kt * 64);
        #pragma unroll
        for (int nt = 0; nt < 10; ++nt) {
            const int d = d0w + nt * 16 + fr;
            const bf16x8 bfr = *(const bf16x8*)(hTb + (long long)d * 512 + kt * 64 + kgb);
            acc[nt] = __builtin_amdgcn_mfma_f32_16x16x32_bf16(afr, bfr, acc[nt], 0, 0, 0);
        }
    }

    // store: lanes 0-15 hold out rows 0-3 in regs; col = d0w + nt*16 + fr
    if ((lane >> 4) == 0) {
        #pragma unroll
        for (int nt = 0; nt < 10; ++nt) {
            const int gc = d0w + nt * 16 + fr;
            #pragma unroll
            for (int r = 0; r < 4; ++r) {
                const float v = fmaxf(acc[nt][r], 0.f);     // relu
                const long long row = (long long)(b * NN + i0 + r);
                if (OUTF32) {
                    if (gc < DD) Of[row * DD + gc] = v;
                } else {
                    Ob[row * KPAD + gc] = __float2bfloat16(v);
                }
            }
        }
    }
}

// ---------------------------------------------------------------------------
// Launch: 7 kernels (prep, then per layer: hGEMM, LR, fused attn_pv)
// ---------------------------------------------------------------------------
extern "C" void kernel_launch(void* const* d_in, const int* in_sizes, int n_in,
                              void* d_out, int out_size, void* d_ws, size_t ws_size,
                              hipStream_t stream)
{
    const float* feature = (const float*)d_in[0];
    const float* adj     = (const float*)d_in[1];
    const float* W0      = (const float*)d_in[2];
    const float* b0      = (const float*)d_in[3];
    const float* W1      = (const float*)d_in[4];
    const float* b1      = (const float*)d_in[5];
    const float* aW1     = (const float*)d_in[6];
    const float* ab1     = (const float*)d_in[7];
    const float* aW2     = (const float*)d_in[8];
    const float* ab2     = (const float*)d_in[9];
    float* out = (float*)d_out;

    __hip_bfloat16* bw = (__hip_bfloat16*)d_ws;
    __hip_bfloat16* xb   = bw;                       // 1024*640
    __hip_bfloat16* W0T  = xb   + MROWS * KPAD;      // 640*640
    __hip_bfloat16* W1T  = W0T  + KPAD * KPAD;       // 640*640
    __hip_bfloat16* aW1T = W1T  + KPAD * KPAD;       // 512*640
    __hip_bfloat16* hb   = aW1T + 512 * KPAD;        // 1024*640
    __hip_bfloat16* hT   = hb   + MROWS * KPAD;      // 4*640*256
    float* LR = (float*)(hT + BATCH * KPAD * NN);    // 1024*512 fp32

    prep_kernel<<<1760, 256, 0, stream>>>(feature, W0, W1, aW1, xb, W0T, W1T, aW1T);

    for (int layer = 0; layer < 2; ++layer) {
        const __hip_bfloat16* WT = layer ? W1T : W0T;
        const float* bb          = layer ? b1 : b0;

        // hb = x @ W + b  [1024][640] bf16 ; also hT[b][d][j]
        gemm_mfma<true, false, true, true, KPAD/64>
            <<<dim3(KPAD / 32, MROWS / 64), 256, 0, stream>>>(
            xb, WT, bb, nullptr, hb, hT,
            KPAD, KPAD, 0, KPAD, 0, DD);

        // LR = hb @ aW1T^T (+ab1 on cols<256)   [1024][512] fp32
        gemm_mfma<true, true, false, false, KPAD/64>
            <<<dim3(512 / 32, MROWS / 64), 256, 0, stream>>>(
            hb, aW1T, ab1, LR, nullptr, nullptr,
            KPAD, KPAD, 512, 0, 512, HH);

        // fused: softmax(mask(leaky(score))) * adj, then @ h -> out rows
        if (layer == 0) {
            attn_pv<false><<<dim3(NN / 4, BATCH), 256, 0, stream>>>(
                LR, aW2, ab2, adj, hT, xb, nullptr);
        } else {
            attn_pv<true><<<dim3(NN / 4, BATCH), 256, 0, stream>>>(
                LR, aW2, ab2, adj, hT, nullptr, out);
        }
    }
}

// Round 14
// 77.566 us; speedup vs baseline: 1.0194x; 1.0194x over previous
//
#include <hip/hip_runtime.h>
#include <hip/hip_bf16.h>

// ---------------------------------------------------------------------------
// Sizes (fixed)
// ---------------------------------------------------------------------------
#define BATCH 4
#define NN    256
#define DD    600
#define HH    256
#define MROWS (BATCH*NN)   // 1024
#define KPAD  640          // DD padded to multiple of 64

typedef __attribute__((ext_vector_type(8))) short bf16x8;   // 8 bf16 (4 VGPRs)
typedef __attribute__((ext_vector_type(4))) float f32x4;

__device__ __forceinline__ void gload16(const void* g, void* l)
{
    __builtin_amdgcn_global_load_lds(
        (const __attribute__((address_space(1))) void*)g,
        (__attribute__((address_space(3))) void*)l, 16, 0, 0);
}

// counted vmcnt wait; n is compile-time after full unroll -> folds to one inst
__device__ __forceinline__ void waitcnt_vm(int n)
{
    switch (n) {
    case 0:  asm volatile("s_waitcnt vmcnt(0)"  ::: "memory"); break;
    case 3:  asm volatile("s_waitcnt vmcnt(3)"  ::: "memory"); break;
    case 6:  asm volatile("s_waitcnt vmcnt(6)"  ::: "memory"); break;
    default: asm volatile("s_waitcnt vmcnt(0)"  ::: "memory"); break;
    }
}

// XCD-chunked bijective remap (m204) of flattened block id
__device__ __forceinline__ int xcd_remap(int lin, int nwg)
{
    const int q = nwg >> 3, r = nwg & 7;
    const int xcd = lin & 7, off = lin >> 3;
    return (xcd < r ? xcd * (q + 1) : r * (q + 1) + (xcd - r) * q) + off;
}

// ---------------------------------------------------------------------------
// bf16 MFMA GEMM (R11, proven): C = A[M,K] @ BT^T (+bias cols<biasN).
// Tile 64M x 32N x 64K, 4 waves (2x2), wave tile 32x16. Ring-4 LDS,
// 3 gload_lds issues/k-tile, counted vmcnt + raw s_barrier.
// WF32: fp32 C (cols<Nvalid). WB16: bf16 C. WHT: hT[b][d][j] retile.
// ---------------------------------------------------------------------------
template<bool BIAS, bool RELU, bool WF32, bool WB16, bool WHT, int NK>
__global__ __launch_bounds__(256) void gemm_mfma(
    const __hip_bfloat16* __restrict__ A, const __hip_bfloat16* __restrict__ BT,
    const float* __restrict__ bias,
    float* __restrict__ Cf, __hip_bfloat16* __restrict__ Cb,
    __hip_bfloat16* __restrict__ hT,
    int lda, int ldb, int ldcf, int ldcb, int Nvalid, int biasN,
    long long sA, long long sBT, long long sCf, long long sCb)
{
    __shared__ __align__(16) char lds[49152];   // A: (t&3)*8K ; B: 32K+(t&3)*4K

    const int nwg = gridDim.x * gridDim.y * gridDim.z;
    int lin = xcd_remap(blockIdx.x + gridDim.x * (blockIdx.y + gridDim.y * blockIdx.z), nwg);
    const int bx = lin % gridDim.x;
    const int by = (lin / gridDim.x) % gridDim.y;
    const int bz = lin / (gridDim.x * gridDim.y);

    const int tid  = threadIdx.x;
    const int lane = tid & 63;
    const int wid  = tid >> 6;
    const int wr   = wid >> 1;          // wave row 0..1 (32 M each)
    const int wc   = wid & 1;           // wave col 0..1 (16 N each)
    const int row0 = by * 64;
    const int col0 = bx * 32;

    const char* Ab = (const char*)A + (bz * sA + (long long)row0 * lda) * 2;
    const char* Bb = (const char*)BT + (bz * sBT + (long long)col0 * ldb) * 2;

    const int sr   = tid >> 3;                    // 0..31
    const int scb  = (tid & 7) * 16;              // 0..112
    const int scbs = scb ^ ((sr & 7) << 4);       // inverse source swizzle

    const char* gA0 = Ab + (long long)sr        * (lda * 2) + scbs;
    const char* gA1 = Ab + (long long)(sr + 32) * (lda * 2) + scbs;
    const char* gB0 = Bb + (long long)sr        * (ldb * 2) + scbs;

    f32x4 acc[2] = {};
    const int fr = lane & 15;
    const int kg = (lane >> 4) * 16;
    const int xv = (fr & 7) << 4;       // read-side XOR swizzle

    auto issue = [&](int t) {
        char* bA = lds + (t & 3) * 8192;
        char* bB = lds + 32768 + (t & 3) * 4096;
        const long long off = (long long)t * 128;
        gload16(gA0 + off, bA + wid * 1024);
        gload16(gA1 + off, bA + 4096 + wid * 1024);
        gload16(gB0 + off, bB + wid * 1024);
    };

    constexpr int PRE = (NK < 3) ? NK : 3;
    #pragma unroll
    for (int p = 0; p < PRE; ++p) issue(p);

    #pragma unroll
    for (int t = 0; t < NK; ++t) {
        const int imax = (t + 2 < NK - 1) ? t + 2 : NK - 1;   // last issued tile
        waitcnt_vm(3 * (imax - t));
        __builtin_amdgcn_s_barrier();
        const char* lA = lds + (t & 3) * 8192;
        const char* lB = lds + 32768 + (t & 3) * 4096;
        #pragma unroll
        for (int ks = 0; ks < 2; ++ks) {
            const int kb = ks * 64 + kg;
            bf16x8 a0 = *(const bf16x8*)(lA + (wr * 32 + fr)      * 128 + (kb ^ xv));
            bf16x8 a1 = *(const bf16x8*)(lA + (wr * 32 + 16 + fr) * 128 + (kb ^ xv));
            bf16x8 b0 = *(const bf16x8*)(lB + (wc * 16 + fr)      * 128 + (kb ^ xv));
            acc[0] = __builtin_amdgcn_mfma_f32_16x16x32_bf16(a0, b0, acc[0], 0, 0, 0);
            acc[1] = __builtin_amdgcn_mfma_f32_16x16x32_bf16(a1, b0, acc[1], 0, 0, 0);
        }
        if (t + 3 < NK) issue(t + 3);
    }
    __syncthreads();

    const int er = (lane >> 4) * 4;
    const int ec = lane & 15;
    __hip_bfloat16* sT = (__hip_bfloat16*)lds;   // [64][40] retile buffer

    #pragma unroll
    for (int mi = 0; mi < 2; ++mi) {
        const int lr0 = wr * 32 + mi * 16 + er;
        const int lc  = wc * 16 + ec;
        const int gr = row0 + lr0;
        const int gc = col0 + lc;
        const float bv = (BIAS && gc < biasN) ? bias[gc] : 0.f;
        #pragma unroll
        for (int r = 0; r < 4; ++r) {
            float v = acc[mi][r] + bv;
            if (RELU) v = fmaxf(v, 0.f);
            const __hip_bfloat16 hv = __float2bfloat16(v);
            const long long row = gr + r;
            if (WF32 && gc < Nvalid)
                Cf[bz * sCf + row * ldcf + gc] = v;
            if (WB16)
                Cb[bz * sCb + row * ldcb + gc] = hv;
            if (WHT)
                sT[(lr0 + r) * 40 + lc] = hv;
        }
    }

    if (WHT) {
        __syncthreads();
        const int b  = row0 >> 8;
        const int i0 = row0 & 255;
        const int cc = tid >> 3;         // 0..31 (d within tile)
        const int ch = tid & 7;          // j-chunk of 8
        const int d = col0 + cc;
        __align__(16) __hip_bfloat16 tmp[8];
        #pragma unroll
        for (int u = 0; u < 8; ++u)
            tmp[u] = sT[(ch * 8 + u) * 40 + cc];
        *(float4*)&hT[((long long)b * KPAD + d) * NN + i0 + ch * 8] = *(float4*)tmp;
    }
}

// ---------------------------------------------------------------------------
// Prep (unchanged, proven): xb cvt + W0T/W1T/aW1T 32x32 LDS transposes.
// ---------------------------------------------------------------------------
__global__ __launch_bounds__(256) void prep_kernel(
    const float* __restrict__ feature, const float* __restrict__ W0,
    const float* __restrict__ W1, const float* __restrict__ aW1,
    __hip_bfloat16* __restrict__ xb, __hip_bfloat16* __restrict__ W0T,
    __hip_bfloat16* __restrict__ W1T, __hip_bfloat16* __restrict__ aW1T)
{
    const int bid = blockIdx.x;
    const int tid = threadIdx.x;
    if (bid < 640) {
        const int idx = (bid * 256 + tid) * 4;
        const int r = idx / KPAD, c = idx % KPAD;
        float4 v = make_float4(0.f, 0.f, 0.f, 0.f);
        if (c < DD) v = *(const float4*)&feature[r * DD + c];   // DD%4==0
        __align__(8) __hip_bfloat16 o[4] = {
            __float2bfloat16(v.x), __float2bfloat16(v.y),
            __float2bfloat16(v.z), __float2bfloat16(v.w)};
        *(float2*)&xb[idx] = *(float2*)o;
        return;
    }
    __shared__ float tile[32][33];
    const int t = bid - 640;
    const int which = (t < 400) ? 0 : (t < 800) ? 1 : 2;
    const int tt = (which == 0) ? t : (which == 1) ? t - 400 : t - 800;
    const int n0 = (tt / 20) * 32;
    const int k0 = (tt % 20) * 32;
    const int tx = tid & 31, ty = tid >> 5;
    #pragma unroll
    for (int r = 0; r < 4; ++r) {
        const int k = k0 + ty + r * 8;
        const int n = n0 + tx;
        float v = 0.f;
        if (which == 0)      { if (k < DD && n < DD) v = W0[k * DD + n]; }
        else if (which == 1) { if (k < DD && n < DD) v = W1[k * DD + n]; }
        else                 { if (k < DD) v = (n < HH) ? aW1[k * HH + n]
                                                        : aW1[(DD + k) * HH + (n - HH)]; }
        tile[ty + r * 8][tx] = v;
    }
    __syncthreads();
    __hip_bfloat16* dst = (which == 0) ? W0T : (which == 1) ? W1T : aW1T;
    #pragma unroll
    for (int r = 0; r < 4; ++r) {
        const int n = n0 + ty + r * 8;
        const int k = k0 + tx;
        dst[n * KPAD + k] = __float2bfloat16(tile[tx][ty + r * 8]);
    }
}

// ---------------------------------------------------------------------------
// Attention: score + leaky_relu + mask + softmax + *adj -> att (bf16)
// Block = (b, 2 rows); thread j. 512 blocks = 2/CU -> 2 waves/SIMD so the
// 64 L2 loads/thread are covered by the second wave (R11 ran 1 wave/SIMD).
// ---------------------------------------------------------------------------
__device__ __forceinline__ void block_max2(float* v, float (*red)[2])
{
    #pragma unroll
    for (int o = 32; o > 0; o >>= 1)
        #pragma unroll
        for (int q = 0; q < 2; ++q) v[q] = fmaxf(v[q], __shfl_down(v[q], o));
    const int lane = threadIdx.x & 63, w = threadIdx.x >> 6;
    if (lane == 0) { red[w][0] = v[0]; red[w][1] = v[1]; }
    __syncthreads();
    #pragma unroll
    for (int q = 0; q < 2; ++q)
        v[q] = fmaxf(fmaxf(red[0][q], red[1][q]), fmaxf(red[2][q], red[3][q]));
    __syncthreads();
}

__device__ __forceinline__ void block_sum2(float* v, float (*red)[2])
{
    #pragma unroll
    for (int o = 32; o > 0; o >>= 1)
        #pragma unroll
        for (int q = 0; q < 2; ++q) v[q] += __shfl_down(v[q], o);
    const int lane = threadIdx.x & 63, w = threadIdx.x >> 6;
    if (lane == 0) { red[w][0] = v[0]; red[w][1] = v[1]; }
    __syncthreads();
    #pragma unroll
    for (int q = 0; q < 2; ++q)
        v[q] = red[0][q] + red[1][q] + red[2][q] + red[3][q];
    __syncthreads();
}

__global__ __launch_bounds__(256) void attn_kernel(
    const float* __restrict__ LR, const float* __restrict__ aW2,
    const float* __restrict__ ab2, const float* __restrict__ adj,
    __hip_bfloat16* __restrict__ att)
{
    __shared__ float sL[2][HH];
    __shared__ float sW[HH];
    __shared__ float red[4][2];

    const int b  = blockIdx.y;
    const int i0 = blockIdx.x * 2;
    const int j  = threadIdx.x;

    // prefetch adj + ab2 early: latency hides under the score loop
    float a[2];
    #pragma unroll
    for (int q = 0; q < 2; ++q)
        a[q] = adj[((long long)(b * NN + i0 + q)) * NN + j];
    const float ab2v = ab2[0];

    sW[j] = aW2[j];
    #pragma unroll
    for (int q = 0; q < 2; ++q)
        sL[q][j] = LR[((long long)(b * NN + i0 + q)) * 512 + j];
    __syncthreads();

    const float* rp = LR + ((long long)(b * NN + j)) * 512 + HH;
    float acc[2] = {0.f, 0.f};
    for (int h = 0; h < HH; h += 8) {
        const float4 ra = *(const float4*)(rp + h);
        const float4 rb = *(const float4*)(rp + h + 4);
        const float4 w0 = *(const float4*)&sW[h];
        const float4 w1 = *(const float4*)&sW[h + 4];
        #pragma unroll
        for (int q = 0; q < 2; ++q) {
            const float4 l0 = *(const float4*)&sL[q][h];
            const float4 l1 = *(const float4*)&sL[q][h + 4];
            float s = fmaxf(l0.x + ra.x, 0.f) * w0.x;
            s += fmaxf(l0.y + ra.y, 0.f) * w0.y;
            s += fmaxf(l0.z + ra.z, 0.f) * w0.z;
            s += fmaxf(l0.w + ra.w, 0.f) * w0.w;
            s += fmaxf(l1.x + rb.x, 0.f) * w1.x;
            s += fmaxf(l1.y + rb.y, 0.f) * w1.y;
            s += fmaxf(l1.z + rb.z, 0.f) * w1.z;
            s += fmaxf(l1.w + rb.w, 0.f) * w1.w;
            acc[q] += s;
        }
    }

    float m[2];
    #pragma unroll
    for (int q = 0; q < 2; ++q) {
        float e = acc[q] + ab2v;
        e = (e > 0.f) ? e : 0.01f * e;                       // leaky_relu
        m[q] = (a[q] == 0.f) ? -1e9f : e;                    // mask
    }
    float mx[2] = {m[0], m[1]};
    block_max2(mx, red);
    float p[2];
    #pragma unroll
    for (int q = 0; q < 2; ++q) p[q] = __expf(m[q] - mx[q]);
    float s[2] = {p[0], p[1]};
    block_sum2(s, red);
    #pragma unroll
    for (int q = 0; q < 2; ++q)
        att[((long long)(b * NN + i0 + q)) * NN + j] = __float2bfloat16(p[q] / s[q] * a[q]);
}

// ---------------------------------------------------------------------------
// Launch
// ---------------------------------------------------------------------------
extern "C" void kernel_launch(void* const* d_in, const int* in_sizes, int n_in,
                              void* d_out, int out_size, void* d_ws, size_t ws_size,
                              hipStream_t stream)
{
    const float* feature = (const float*)d_in[0];
    const float* adj     = (const float*)d_in[1];
    const float* W0      = (const float*)d_in[2];
    const float* b0      = (const float*)d_in[3];
    const float* W1      = (const float*)d_in[4];
    const float* b1      = (const float*)d_in[5];
    const float* aW1     = (const float*)d_in[6];
    const float* ab1     = (const float*)d_in[7];
    const float* aW2     = (const float*)d_in[8];
    const float* ab2     = (const float*)d_in[9];
    float* out = (float*)d_out;

    __hip_bfloat16* bw = (__hip_bfloat16*)d_ws;
    __hip_bfloat16* xb   = bw;                       // 1024*640
    __hip_bfloat16* W0T  = xb   + MROWS * KPAD;      // 640*640
    __hip_bfloat16* W1T  = W0T  + KPAD * KPAD;       // 640*640
    __hip_bfloat16* aW1T = W1T  + KPAD * KPAD;       // 512*640
    __hip_bfloat16* hb   = aW1T + 512 * KPAD;        // 1024*640
    __hip_bfloat16* hT   = hb   + MROWS * KPAD;      // 4*640*256
    __hip_bfloat16* att  = hT   + BATCH * KPAD * NN; // 4*256*256
    float* LR = (float*)(att + BATCH * NN * NN);     // 1024*512 fp32

    prep_kernel<<<1760, 256, 0, stream>>>(feature, W0, W1, aW1, xb, W0T, W1T, aW1T);

    for (int layer = 0; layer < 2; ++layer) {
        const __hip_bfloat16* WT = layer ? W1T : W0T;
        const float* bb          = layer ? b1 : b0;

        // hb = x @ W + b  [1024][640] bf16 ; also hT[b][d][j]
        gemm_mfma<true, false, false, true, true, KPAD/64>
            <<<dim3(KPAD / 32, MROWS / 64, 1), 256, 0, stream>>>(
            xb, WT, bb, nullptr, hb, hT,
            KPAD, KPAD, 0, KPAD, 0, DD, 0, 0, 0, 0);

        // LR = hb @ aW1T^T (+ab1 on cols<256)   [1024][512] fp32
        gemm_mfma<true, false, true, false, false, KPAD/64>
            <<<dim3(512 / 32, MROWS / 64, 1), 256, 0, stream>>>(
            hb, aW1T, ab1, LR, nullptr, nullptr,
            KPAD, KPAD, 512, 0, 512, HH, 0, 0, 0, 0);

        // att = softmax(mask(leaky(score))) * adj   bf16  (2 rows/block)
        attn_kernel<<<dim3(NN / 2, BATCH), 256, 0, stream>>>(LR, aW2, ab2, adj, att);

        // out = relu(att @ h): layer0 -> xb (bf16); layer1 -> out fp32
        if (layer == 0) {
            gemm_mfma<false, true, false, true, false, NN/64>
                <<<dim3(KPAD / 32, NN / 64, BATCH), 256, 0, stream>>>(
                att, hT, nullptr, nullptr, xb, nullptr,
                NN, NN, 0, KPAD, 0, 0,
                (long long)NN * NN, (long long)KPAD * NN, 0, (long long)NN * KPAD);
        } else {
            gemm_mfma<false, true, true, false, false, NN/64>
                <<<dim3(KPAD / 32, NN / 64, BATCH), 256, 0, stream>>>(
                att, hT, nullptr, out, nullptr, nullptr,
                NN, NN, DD, 0, DD, 0,
                (long long)NN * NN, (long long)KPAD * NN, (long long)NN * DD, 0);
        }
    }
}

// Round 15
// 64.524 us; speedup vs baseline: 1.2254x; 1.2021x over previous
//
#include <hip/hip_runtime.h>
#include <hip/hip_bf16.h>

// ---------------------------------------------------------------------------
// Sizes (fixed)
// ---------------------------------------------------------------------------
#define BATCH 4
#define NN    256
#define DD    600
#define HH    256
#define MROWS (BATCH*NN)   // 1024
#define KPAD  640          // DD padded to multiple of 64

typedef __attribute__((ext_vector_type(8))) short bf16x8;   // 8 bf16 (4 VGPRs)
typedef __attribute__((ext_vector_type(4))) float f32x4;

__device__ __forceinline__ void gload16(const void* g, void* l)
{
    __builtin_amdgcn_global_load_lds(
        (const __attribute__((address_space(1))) void*)g,
        (__attribute__((address_space(3))) void*)l, 16, 0, 0);
}

// counted vmcnt wait; n is compile-time after full unroll -> folds to one inst
__device__ __forceinline__ void waitcnt_vm(int n)
{
    switch (n) {
    case 0:  asm volatile("s_waitcnt vmcnt(0)"  ::: "memory"); break;
    case 3:  asm volatile("s_waitcnt vmcnt(3)"  ::: "memory"); break;
    case 6:  asm volatile("s_waitcnt vmcnt(6)"  ::: "memory"); break;
    default: asm volatile("s_waitcnt vmcnt(0)"  ::: "memory"); break;
    }
}

// XCD-chunked bijective remap (m204) of flattened block id
__device__ __forceinline__ int xcd_remap(int lin, int nwg)
{
    const int q = nwg >> 3, r = nwg & 7;
    const int xcd = lin & 7, off = lin >> 3;
    return (xcd < r ? xcd * (q + 1) : r * (q + 1) + (xcd - r) * q) + off;
}

// ---------------------------------------------------------------------------
// bf16 MFMA GEMM: C = A[M,K] @ BT^T (+bias cols<biasN) (+relu), K = NK*64.
// Tile 64M x 32N x 64K, 256 threads = 4 waves (2x2), wave tile 32x16.
// Ring-4 LDS (A 8K x4 + B 4K x4 = 48 KB); 3 gload_lds issues per k-tile;
// counted vmcnt (3 per in-flight tile) + raw s_barrier (T3/T4).
// Grid x = N/32, y = M/64 (z batches) -> all 256 CUs occupied.
// WF32: fp32 C (cols<Nvalid). WB16: bf16 C (all cols).
// WHT: also write hT[b][d][j] via LDS retile (M must be 1024 = 4b x 256j).
// LDS XOR-swizzle (T2/m201): linear global_load_lds dest + inverse-swizzled
// global source + swizzled ds_read_b128.
// ---------------------------------------------------------------------------
template<bool BIAS, bool RELU, bool WF32, bool WB16, bool WHT, int NK>
__global__ __launch_bounds__(256) void gemm_mfma(
    const __hip_bfloat16* __restrict__ A, const __hip_bfloat16* __restrict__ BT,
    const float* __restrict__ bias,
    float* __restrict__ Cf, __hip_bfloat16* __restrict__ Cb,
    __hip_bfloat16* __restrict__ hT,
    int lda, int ldb, int ldcf, int ldcb, int Nvalid, int biasN,
    long long sA, long long sBT, long long sCf, long long sCb)
{
    __shared__ __align__(16) char lds[49152];   // A: (t&3)*8K ; B: 32K+(t&3)*4K

    const int nwg = gridDim.x * gridDim.y * gridDim.z;
    int lin = xcd_remap(blockIdx.x + gridDim.x * (blockIdx.y + gridDim.y * blockIdx.z), nwg);
    const int bx = lin % gridDim.x;
    const int by = (lin / gridDim.x) % gridDim.y;
    const int bz = lin / (gridDim.x * gridDim.y);

    const int tid  = threadIdx.x;
    const int lane = tid & 63;
    const int wid  = tid >> 6;
    const int wr   = wid >> 1;          // wave row 0..1 (32 M each)
    const int wc   = wid & 1;           // wave col 0..1 (16 N each)
    const int row0 = by * 64;
    const int col0 = bx * 32;

    const char* Ab = (const char*)A + (bz * sA + (long long)row0 * lda) * 2;
    const char* Bb = (const char*)BT + (bz * sBT + (long long)col0 * ldb) * 2;

    const int sr   = tid >> 3;                    // 0..31
    const int scb  = (tid & 7) * 16;              // 0..112
    const int scbs = scb ^ ((sr & 7) << 4);       // inverse source swizzle

    const char* gA0 = Ab + (long long)sr        * (lda * 2) + scbs;
    const char* gA1 = Ab + (long long)(sr + 32) * (lda * 2) + scbs;
    const char* gB0 = Bb + (long long)sr        * (ldb * 2) + scbs;

    f32x4 acc[2] = {};
    const int fr = lane & 15;
    const int kg = (lane >> 4) * 16;
    const int xv = (fr & 7) << 4;       // read-side XOR swizzle

    auto issue = [&](int t) {
        char* bA = lds + (t & 3) * 8192;
        char* bB = lds + 32768 + (t & 3) * 4096;
        const long long off = (long long)t * 128;
        gload16(gA0 + off, bA + wid * 1024);
        gload16(gA1 + off, bA + 4096 + wid * 1024);
        gload16(gB0 + off, bB + wid * 1024);
    };

    constexpr int PRE = (NK < 3) ? NK : 3;
    #pragma unroll
    for (int p = 0; p < PRE; ++p) issue(p);

    #pragma unroll
    for (int t = 0; t < NK; ++t) {
        const int imax = (t + 2 < NK - 1) ? t + 2 : NK - 1;   // last issued tile
        waitcnt_vm(3 * (imax - t));          // tile t's 3 loads complete
        __builtin_amdgcn_s_barrier();        // all waves' loads for tile t landed
        const char* lA = lds + (t & 3) * 8192;
        const char* lB = lds + 32768 + (t & 3) * 4096;
        #pragma unroll
        for (int ks = 0; ks < 2; ++ks) {
            const int kb = ks * 64 + kg;
            bf16x8 a0 = *(const bf16x8*)(lA + (wr * 32 + fr)      * 128 + (kb ^ xv));
            bf16x8 a1 = *(const bf16x8*)(lA + (wr * 32 + 16 + fr) * 128 + (kb ^ xv));
            bf16x8 b0 = *(const bf16x8*)(lB + (wc * 16 + fr)      * 128 + (kb ^ xv));
            acc[0] = __builtin_amdgcn_mfma_f32_16x16x32_bf16(a0, b0, acc[0], 0, 0, 0);
            acc[1] = __builtin_amdgcn_mfma_f32_16x16x32_bf16(a1, b0, acc[1], 0, 0, 0);
        }
        if (t + 3 < NK) issue(t + 3);        // into buffer (t-1)&3: reads done pre-barrier
    }
    __syncthreads();                          // all LDS reads done (sT reuse below)

    // epilogue: C/D frag mapping col=lane&15, row=(lane>>4)*4+reg
    const int er = (lane >> 4) * 4;
    const int ec = lane & 15;
    __hip_bfloat16* sT = (__hip_bfloat16*)lds;   // [64][40] retile buffer

    #pragma unroll
    for (int mi = 0; mi < 2; ++mi) {
        const int lr0 = wr * 32 + mi * 16 + er;
        const int lc  = wc * 16 + ec;
        const int gr = row0 + lr0;
        const int gc = col0 + lc;
        const float bv = (BIAS && gc < biasN) ? bias[gc] : 0.f;
        #pragma unroll
        for (int r = 0; r < 4; ++r) {
            float v = acc[mi][r] + bv;
            if (RELU) v = fmaxf(v, 0.f);
            const __hip_bfloat16 hv = __float2bfloat16(v);
            const long long row = gr + r;
            if (WF32 && gc < Nvalid)
                Cf[bz * sCf + row * ldcf + gc] = v;
            if (WB16)
                Cb[bz * sCb + row * ldcb + gc] = hv;
            if (WHT)
                sT[(lr0 + r) * 40 + lc] = hv;
        }
    }

    if (WHT) {
        __syncthreads();
        const int b  = row0 >> 8;
        const int i0 = row0 & 255;
        const int cc = tid >> 3;         // 0..31 (d within tile)
        const int ch = tid & 7;          // j-chunk of 8
        const int d = col0 + cc;
        __align__(16) __hip_bfloat16 tmp[8];
        #pragma unroll
        for (int u = 0; u < 8; ++u)
            tmp[u] = sT[(ch * 8 + u) * 40 + cc];
        *(float4*)&hT[((long long)b * KPAD + d) * NN + i0 + ch * 8] = *(float4*)tmp;
    }
}

// ---------------------------------------------------------------------------
// Prep: xb = bf16(pad(feature)) vectorized; W0T/W1T/aW1T via 32x32 LDS
// tile transpose (coalesced both sides) + bf16 convert.
// ---------------------------------------------------------------------------
__global__ __launch_bounds__(256) void prep_kernel(
    const float* __restrict__ feature, const float* __restrict__ W0,
    const float* __restrict__ W1, const float* __restrict__ aW1,
    __hip_bfloat16* __restrict__ xb, __hip_bfloat16* __restrict__ W0T,
    __hip_bfloat16* __restrict__ W1T, __hip_bfloat16* __restrict__ aW1T)
{
    const int bid = blockIdx.x;
    const int tid = threadIdx.x;
    if (bid < 640) {
        const int idx = (bid * 256 + tid) * 4;
        const int r = idx / KPAD, c = idx % KPAD;
        float4 v = make_float4(0.f, 0.f, 0.f, 0.f);
        if (c < DD) v = *(const float4*)&feature[r * DD + c];   // DD%4==0
        __align__(8) __hip_bfloat16 o[4] = {
            __float2bfloat16(v.x), __float2bfloat16(v.y),
            __float2bfloat16(v.z), __float2bfloat16(v.w)};
        *(float2*)&xb[idx] = *(float2*)o;
        return;
    }
    __shared__ float tile[32][33];
    const int t = bid - 640;
    const int which = (t < 400) ? 0 : (t < 800) ? 1 : 2;
    const int tt = (which == 0) ? t : (which == 1) ? t - 400 : t - 800;
    const int n0 = (tt / 20) * 32;
    const int k0 = (tt % 20) * 32;
    const int tx = tid & 31, ty = tid >> 5;
    #pragma unroll
    for (int r = 0; r < 4; ++r) {
        const int k = k0 + ty + r * 8;
        const int n = n0 + tx;
        float v = 0.f;
        if (which == 0)      { if (k < DD && n < DD) v = W0[k * DD + n]; }
        else if (which == 1) { if (k < DD && n < DD) v = W1[k * DD + n]; }
        else                 { if (k < DD) v = (n < HH) ? aW1[k * HH + n]
                                                        : aW1[(DD + k) * HH + (n - HH)]; }
        tile[ty + r * 8][tx] = v;
    }
    __syncthreads();
    __hip_bfloat16* dst = (which == 0) ? W0T : (which == 1) ? W1T : aW1T;
    #pragma unroll
    for (int r = 0; r < 4; ++r) {
        const int n = n0 + ty + r * 8;
        const int k = k0 + tx;
        dst[n * KPAD + k] = __float2bfloat16(tile[tx][ty + r * 8]);
    }
}

// ---------------------------------------------------------------------------
// Attention: score + leaky_relu + mask + softmax + *adj -> att (bf16)
// Block = (b, 4 rows); thread j. 256 blocks (1/CU). adj prefetched before
// the h-loop so its latency hides under the score compute. R-panel read
// (256 KB/block) is amortized over 4 rows — do NOT reduce rows/block (R14).
// ---------------------------------------------------------------------------
__device__ __forceinline__ void block_max4(float* v, float (*red)[4])
{
    #pragma unroll
    for (int o = 32; o > 0; o >>= 1)
        #pragma unroll
        for (int q = 0; q < 4; ++q) v[q] = fmaxf(v[q], __shfl_down(v[q], o));
    const int lane = threadIdx.x & 63, w = threadIdx.x >> 6;
    if (lane == 0) { red[w][0]=v[0]; red[w][1]=v[1]; red[w][2]=v[2]; red[w][3]=v[3]; }
    __syncthreads();
    #pragma unroll
    for (int q = 0; q < 4; ++q)
        v[q] = fmaxf(fmaxf(red[0][q], red[1][q]), fmaxf(red[2][q], red[3][q]));
    __syncthreads();
}

__device__ __forceinline__ void block_sum4(float* v, float (*red)[4])
{
    #pragma unroll
    for (int o = 32; o > 0; o >>= 1)
        #pragma unroll
        for (int q = 0; q < 4; ++q) v[q] += __shfl_down(v[q], o);
    const int lane = threadIdx.x & 63, w = threadIdx.x >> 6;
    if (lane == 0) { red[w][0]=v[0]; red[w][1]=v[1]; red[w][2]=v[2]; red[w][3]=v[3]; }
    __syncthreads();
    #pragma unroll
    for (int q = 0; q < 4; ++q)
        v[q] = red[0][q] + red[1][q] + red[2][q] + red[3][q];
    __syncthreads();
}

__global__ __launch_bounds__(256) void attn_kernel(
    const float* __restrict__ LR, const float* __restrict__ aW2,
    const float* __restrict__ ab2, const float* __restrict__ adj,
    __hip_bfloat16* __restrict__ att)
{
    __shared__ float sL[4][HH];
    __shared__ float sW[HH];
    __shared__ float red[4][4];

    const int b  = blockIdx.y;
    const int i0 = blockIdx.x * 4;
    const int j  = threadIdx.x;

    // prefetch adj + ab2 early: latency hides under the 256-iter score loop
    float a[4];
    #pragma unroll
    for (int q = 0; q < 4; ++q)
        a[q] = adj[((long long)(b * NN + i0 + q)) * NN + j];
    const float ab2v = ab2[0];

    sW[j] = aW2[j];
    #pragma unroll
    for (int q = 0; q < 4; ++q)
        sL[q][j] = LR[((long long)(b * NN + i0 + q)) * 512 + j];
    __syncthreads();

    const float* rp = LR + ((long long)(b * NN + j)) * 512 + HH;
    float acc[4] = {0.f, 0.f, 0.f, 0.f};
    for (int h = 0; h < HH; h += 8) {
        const float4 ra = *(const float4*)(rp + h);
        const float4 rb = *(const float4*)(rp + h + 4);
        const float4 w0 = *(const float4*)&sW[h];
        const float4 w1 = *(const float4*)&sW[h + 4];
        #pragma unroll
        for (int q = 0; q < 4; ++q) {
            const float4 l0 = *(const float4*)&sL[q][h];
            const float4 l1 = *(const float4*)&sL[q][h + 4];
            float s = fmaxf(l0.x + ra.x, 0.f) * w0.x;
            s += fmaxf(l0.y + ra.y, 0.f) * w0.y;
            s += fmaxf(l0.z + ra.z, 0.f) * w0.z;
            s += fmaxf(l0.w + ra.w, 0.f) * w0.w;
            s += fmaxf(l1.x + rb.x, 0.f) * w1.x;
            s += fmaxf(l1.y + rb.y, 0.f) * w1.y;
            s += fmaxf(l1.z + rb.z, 0.f) * w1.z;
            s += fmaxf(l1.w + rb.w, 0.f) * w1.w;
            acc[q] += s;
        }
    }

    float m[4];
    #pragma unroll
    for (int q = 0; q < 4; ++q) {
        float e = acc[q] + ab2v;
        e = (e > 0.f) ? e : 0.01f * e;                       // leaky_relu
        m[q] = (a[q] == 0.f) ? -1e9f : e;                    // mask
    }
    float mx[4] = {m[0], m[1], m[2], m[3]};
    block_max4(mx, red);
    float p[4];
    #pragma unroll
    for (int q = 0; q < 4; ++q) p[q] = __expf(m[q] - mx[q]);
    float s[4] = {p[0], p[1], p[2], p[3]};
    block_sum4(s, red);
    #pragma unroll
    for (int q = 0; q < 4; ++q)
        att[((long long)(b * NN + i0 + q)) * NN + j] = __float2bfloat16(p[q] / s[q] * a[q]);
}

// ---------------------------------------------------------------------------
// Launch
// ---------------------------------------------------------------------------
extern "C" void kernel_launch(void* const* d_in, const int* in_sizes, int n_in,
                              void* d_out, int out_size, void* d_ws, size_t ws_size,
                              hipStream_t stream)
{
    const float* feature = (const float*)d_in[0];
    const float* adj     = (const float*)d_in[1];
    const float* W0      = (const float*)d_in[2];
    const float* b0      = (const float*)d_in[3];
    const float* W1      = (const float*)d_in[4];
    const float* b1      = (const float*)d_in[5];
    const float* aW1     = (const float*)d_in[6];
    const float* ab1     = (const float*)d_in[7];
    const float* aW2     = (const float*)d_in[8];
    const float* ab2     = (const float*)d_in[9];
    float* out = (float*)d_out;

    __hip_bfloat16* bw = (__hip_bfloat16*)d_ws;
    __hip_bfloat16* xb   = bw;                       // 1024*640
    __hip_bfloat16* W0T  = xb   + MROWS * KPAD;      // 640*640
    __hip_bfloat16* W1T  = W0T  + KPAD * KPAD;      // 640*640
    __hip_bfloat16* aW1T = W1T  + KPAD * KPAD;       // 512*640
    __hip_bfloat16* hb   = aW1T + 512 * KPAD;        // 1024*640
    __hip_bfloat16* hT   = hb   + MROWS * KPAD;      // 4*640*256
    __hip_bfloat16* att  = hT   + BATCH * KPAD * NN; // 4*256*256
    float* LR = (float*)(att + BATCH * NN * NN);     // 1024*512 fp32

    prep_kernel<<<1760, 256, 0, stream>>>(feature, W0, W1, aW1, xb, W0T, W1T, aW1T);

    for (int layer = 0; layer < 2; ++layer) {
        const __hip_bfloat16* WT = layer ? W1T : W0T;
        const float* bb          = layer ? b1 : b0;

        // hb = x @ W + b  [1024][640] bf16 ; also hT[b][d][j]
        gemm_mfma<true, false, false, true, true, KPAD/64>
            <<<dim3(KPAD / 32, MROWS / 64, 1), 256, 0, stream>>>(
            xb, WT, bb, nullptr, hb, hT,
            KPAD, KPAD, 0, KPAD, 0, DD, 0, 0, 0, 0);

        // LR = hb @ aW1T^T (+ab1 on cols<256)   [1024][512] fp32
        gemm_mfma<true, false, true, false, false, KPAD/64>
            <<<dim3(512 / 32, MROWS / 64, 1), 256, 0, stream>>>(
            hb, aW1T, ab1, LR, nullptr, nullptr,
            KPAD, KPAD, 512, 0, 512, HH, 0, 0, 0, 0);

        // att = softmax(mask(leaky(score))) * adj   bf16
        attn_kernel<<<dim3(NN / 4, BATCH), 256, 0, stream>>>(LR, aW2, ab2, adj, att);

        // out = relu(att @ h): layer0 -> xb (bf16); layer1 -> out fp32
        if (layer == 0) {
            gemm_mfma<false, true, false, true, false, NN/64>
                <<<dim3(KPAD / 32, NN / 64, BATCH), 256, 0, stream>>>(
                att, hT, nullptr, nullptr, xb, nullptr,
                NN, NN, 0, KPAD, 0, 0,
                (long long)NN * NN, (long long)KPAD * NN, 0, (long long)NN * KPAD);
        } else {
            gemm_mfma<false, true, true, false, false, NN/64>
                <<<dim3(KPAD / 32, NN / 64, BATCH), 256, 0, stream>>>(
                att, hT, nullptr, out, nullptr, nullptr,
                NN, NN, DD, 0, DD, 0,
                (long long)NN * NN, (long long)KPAD * NN, (long long)NN * DD, 0);
        }
    }
}